// Round 3
// baseline (471.545 us; speedup 1.0000x reference)
//
#include <hip/hip_runtime.h>

// Problem dims (fixed)
#define BB 8
#define TT 1024
#define DD 1024
#define HH 16
#define AA 64
#define EE 262144

typedef unsigned short u16;
typedef short bf16x8 __attribute__((ext_vector_type(8)));
typedef float f32x4 __attribute__((ext_vector_type(4)));

__device__ __forceinline__ float bf2f(u16 u) {
    union { float f; unsigned int i; } c; c.i = ((unsigned int)u) << 16; return c.f;
}
__device__ __forceinline__ u16 f2bf(float f) {
    union { float f; unsigned int i; } c; c.f = f;
    unsigned int x = c.i;
    unsigned int r = (x + 0x7FFFu + ((x >> 16) & 1u)) >> 16;
    return (u16)r;
}

// ---------------------------------------------------------------------------
// Kernel 0: elementwise f32 -> bf16 (8 elems/thread)
// ---------------------------------------------------------------------------
__global__ __launch_bounds__(256) void cvt(const float* __restrict__ src,
                                           u16* __restrict__ dst) {
    size_t i = ((size_t)blockIdx.x * 256 + threadIdx.x) * 8;
    f32x4 a = *(const f32x4*)(src + i);
    f32x4 b = *(const f32x4*)(src + i + 4);
    bf16x8 o;
#pragma unroll
    for (int j = 0; j < 4; j++) { o[j] = (short)f2bf(a[j]); o[4 + j] = (short)f2bf(b[j]); }
    *(bf16x8*)(dst + i) = o;
}

// ---------------------------------------------------------------------------
// Kernel 1: transpose 4 f32 weight matrices (1024x1024) -> bf16 (N,K) layout
// ---------------------------------------------------------------------------
__global__ __launch_bounds__(256) void tr_w(const float* __restrict__ s0,
                                            const float* __restrict__ s1,
                                            const float* __restrict__ s2,
                                            const float* __restrict__ s3,
                                            u16* __restrict__ dstbase) {
    __shared__ u16 t[64 * 72];
    int tid = threadIdx.x;
    int z = blockIdx.z;
    const float* src = (z == 0) ? s0 : (z == 1) ? s1 : (z == 2) ? s2 : s3;
    u16* dst = dstbase + (size_t)z * 1024 * 1024;
    int row0 = blockIdx.y * 64, col0 = blockIdx.x * 64;
    int r = tid >> 2, c0 = (tid & 3) * 16;
    const float* sp = src + (size_t)(row0 + r) * 1024 + col0 + c0;
    f32x4 f0 = *(const f32x4*)(sp);
    f32x4 f1 = *(const f32x4*)(sp + 4);
    f32x4 f2_ = *(const f32x4*)(sp + 8);
    f32x4 f3 = *(const f32x4*)(sp + 12);
#pragma unroll
    for (int j = 0; j < 4; j++) {
        t[r * 72 + c0 + j] = f2bf(f0[j]);
        t[r * 72 + c0 + 4 + j] = f2bf(f1[j]);
        t[r * 72 + c0 + 8 + j] = f2bf(f2_[j]);
        t[r * 72 + c0 + 12 + j] = f2bf(f3[j]);
    }
    __syncthreads();
    // dst[col0+r][row0+c0+j] = t[c0+j][r]  (dst[n][k] = src[k][n])
    bf16x8 o0, o1;
#pragma unroll
    for (int j = 0; j < 8; j++) o0[j] = (short)t[(c0 + j) * 72 + r];
#pragma unroll
    for (int j = 0; j < 8; j++) o1[j] = (short)t[(c0 + 8 + j) * 72 + r];
    *(bf16x8*)(dst + (size_t)(col0 + r) * 1024 + row0 + c0) = o0;
    *(bf16x8*)(dst + (size_t)(col0 + r) * 1024 + row0 + c0 + 8) = o1;
}

// ---------------------------------------------------------------------------
// Kernel 2a: scatter pass 1 — last edge index wins (numpy scatter semantics)
// ---------------------------------------------------------------------------
__global__ __launch_bounds__(256) void scat_max(const int* __restrict__ ab,
                                                int* __restrict__ idx) {
    int e = blockIdx.x * 256 + threadIdx.x;
    const int* rec = ab + (size_t)e * 4;
    int b = rec[1], q = rec[2], k = rec[3];
    atomicMax(&idx[((((size_t)b << 10) + q) << 10) + k], e);
}

// Kernel 2b: scatter pass 2 — winner writes projected value (f32 params)
__global__ __launch_bounds__(256) void scat_res(const int* __restrict__ ab,
                                                const int* __restrict__ idx,
                                                const float* __restrict__ be,
                                                const float* __restrict__ bsc,
                                                float* __restrict__ bs) {
    __shared__ float proj[32];
    int tid = threadIdx.x;
    if (tid < 32) {
        float s = 0.f;
        for (int a = 0; a < 64; a++) s += be[tid * 64 + a] * bsc[a];
        proj[tid] = s;
    }
    __syncthreads();
    int e = blockIdx.x * 256 + tid;
    const int* rec = ab + (size_t)e * 4;
    int et = rec[0], b = rec[1], q = rec[2], k = rec[3];
    size_t cell = ((((size_t)b << 10) + q) << 10) + k;
    if (idx[cell] == e) bs[cell] = proj[et];
}

// ---------------------------------------------------------------------------
// Kernel 3: bf16 MFMA GEMM, M=8192 N=1024 K=1024, 128x128 tile, BK=32
// A bf16 row-major (M,K), BT bf16 row-major (N,K).
// mode 0: C f32 row-major (M,N).  mode 1: C bf16 -> [B,H,T,A]
// ---------------------------------------------------------------------------
__global__ __launch_bounds__(256) void gemm128(const u16* __restrict__ A,
                                               const u16* __restrict__ BT,
                                               void* __restrict__ C, int mode) {
    __shared__ u16 Asm[128 * 40];
    __shared__ u16 Bsm[128 * 40];
    int tid = threadIdx.x;
    int wave = tid >> 6, lane = tid & 63;
    int quad = lane >> 4, l16 = lane & 15;
    int wm = wave >> 1, wn = wave & 1;
    int mbase = blockIdx.y * 128, nbase = blockIdx.x * 128;
    f32x4 acc[4][4] = {};
    int srow = tid >> 1;
    int scol = (tid & 1) * 16;
    const u16* Ag = A + (size_t)(mbase + srow) * 1024 + scol;
    const u16* Bg = BT + (size_t)(nbase + srow) * 1024 + scol;
    for (int k0 = 0; k0 < 1024; k0 += 32) {
        bf16x8 a0 = *(const bf16x8*)(Ag + k0);
        bf16x8 a1 = *(const bf16x8*)(Ag + k0 + 8);
        bf16x8 b0 = *(const bf16x8*)(Bg + k0);
        bf16x8 b1 = *(const bf16x8*)(Bg + k0 + 8);
        __syncthreads();
        *(bf16x8*)&Asm[srow * 40 + scol] = a0;
        *(bf16x8*)&Asm[srow * 40 + scol + 8] = a1;
        *(bf16x8*)&Bsm[srow * 40 + scol] = b0;
        *(bf16x8*)&Bsm[srow * 40 + scol + 8] = b1;
        __syncthreads();
        bf16x8 af[4], bfr[4];
#pragma unroll
        for (int mt = 0; mt < 4; mt++)
            af[mt] = *(const bf16x8*)&Asm[(wm * 64 + mt * 16 + l16) * 40 + quad * 8];
#pragma unroll
        for (int nt = 0; nt < 4; nt++)
            bfr[nt] = *(const bf16x8*)&Bsm[(wn * 64 + nt * 16 + l16) * 40 + quad * 8];
#pragma unroll
        for (int mt = 0; mt < 4; mt++)
#pragma unroll
            for (int nt = 0; nt < 4; nt++)
                acc[mt][nt] = __builtin_amdgcn_mfma_f32_16x16x32_bf16(af[mt], bfr[nt], acc[mt][nt], 0, 0, 0);
    }
#pragma unroll
    for (int mt = 0; mt < 4; mt++)
#pragma unroll
        for (int nt = 0; nt < 4; nt++)
#pragma unroll
            for (int r = 0; r < 4; r++) {
                int gm = mbase + wm * 64 + mt * 16 + quad * 4 + r;
                int gn = nbase + wn * 64 + nt * 16 + l16;
                if (mode == 0) {
                    ((float*)C)[(size_t)gm * 1024 + gn] = acc[mt][nt][r];
                } else {
                    int b = gm >> 10, t = gm & 1023, h = gn >> 6, a = gn & 63;
                    ((u16*)C)[(((size_t)(b * 16 + h) * 1024) + t) * 64 + a] = f2bf(acc[mt][nt][r]);
                }
            }
}

// ---------------------------------------------------------------------------
// Kernel 4: transpose v [B,H,T,A] -> vT [B,H,A,T]  (bf16)
// ---------------------------------------------------------------------------
__global__ __launch_bounds__(256) void tr_v(const u16* __restrict__ v,
                                            u16* __restrict__ vT) {
    __shared__ u16 t[64 * 72];
    int tid = threadIdx.x;
    int bh = blockIdx.y;
    int t0 = blockIdx.x * 64;
    int r = tid >> 2, c0 = (tid & 3) * 16;
    const u16* src = v + (size_t)bh * 1024 * 64;
    u16* dst = vT + (size_t)bh * 64 * 1024;
    bf16x8 v0 = *(const bf16x8*)(src + (size_t)(t0 + r) * 64 + c0);
    bf16x8 v1 = *(const bf16x8*)(src + (size_t)(t0 + r) * 64 + c0 + 8);
    *(bf16x8*)&t[r * 72 + c0] = v0;
    *(bf16x8*)&t[r * 72 + c0 + 8] = v1;
    __syncthreads();
    bf16x8 o0, o1;
#pragma unroll
    for (int j = 0; j < 8; j++) o0[j] = (short)t[(c0 + j) * 72 + r];
#pragma unroll
    for (int j = 0; j < 8; j++) o1[j] = (short)t[(c0 + 8 + j) * 72 + r];
    *(bf16x8*)(dst + (size_t)r * 1024 + t0 + c0) = o0;
    *(bf16x8*)(dst + (size_t)r * 1024 + t0 + c0 + 8) = o1;
}

// ---------------------------------------------------------------------------
// Kernel 5: ksum[b,h,t] = sum_a k[b,h,t,a]  (bf16 in, f32 out)
// ---------------------------------------------------------------------------
__global__ __launch_bounds__(256) void ksumk(const u16* __restrict__ k,
                                             float* __restrict__ ks) {
    int i = blockIdx.x * 256 + threadIdx.x;  // 131072 total
    const u16* kp = k + (size_t)i * 64;
    float s = 0.f;
#pragma unroll
    for (int c = 0; c < 64; c += 8) {
        bf16x8 v = *(const bf16x8*)(kp + c);
#pragma unroll
        for (int j = 0; j < 8; j++) s += bf2f((u16)v[j]);
    }
    ks[i] = s;
}

// ---------------------------------------------------------------------------
// Kernel 6: flash attention per (q-tile 64, h, b).
// q,k: [B,H,T,A] bf16; vT: [B,H,A,T] bf16; ksum: [B,H,T] f32; bs: [B,T,T] f32;
// masks: [B,T,T] f32; out ctx: [B,T,H,A] bf16.
// ---------------------------------------------------------------------------
__global__ __launch_bounds__(256) void attn(const u16* __restrict__ qbuf,
                                            const u16* __restrict__ kbuf,
                                            const u16* __restrict__ vT,
                                            const float* __restrict__ ksum,
                                            const float* __restrict__ bs,
                                            const float* __restrict__ masks,
                                            u16* __restrict__ ctx) {
    __shared__ u16 Ksm[64 * 72];
    __shared__ u16 Vsm[64 * 72];
    __shared__ u16 Psm[4 * 16 * 72];
    __shared__ float sksm[64];
    int tid = threadIdx.x;
    int wave = tid >> 6, lane = tid & 63;
    int quad = lane >> 4, l16 = lane & 15;
    int qb = blockIdx.x, h = blockIdx.y, b = blockIdx.z;
    int bh = b * 16 + h;
    const u16* qp = qbuf + (size_t)bh * 1024 * 64;
    const u16* kp = kbuf + (size_t)bh * 1024 * 64;
    const u16* vp = vT + (size_t)bh * 64 * 1024;
    const float* ksp = ksum + (size_t)bh * 1024;
    const float* bsp = bs + (size_t)b * 1024 * 1024;
    const float* mp = masks + (size_t)b * 1024 * 1024;
    int q0 = qb * 64 + wave * 16;

    bf16x8 qf[2];
    qf[0] = *(const bf16x8*)(qp + (size_t)(q0 + l16) * 64 + quad * 8);
    qf[1] = *(const bf16x8*)(qp + (size_t)(q0 + l16) * 64 + 32 + quad * 8);

    f32x4 oacc[4] = {};
    float m_i[4], l_i[4];
#pragma unroll
    for (int r = 0; r < 4; r++) { m_i[r] = -3.0e38f; l_i[r] = 0.f; }

    int srow = tid >> 2, sc0 = (tid & 3) * 16;
    u16* pw = &Psm[wave * 16 * 72];

    for (int kb = 0; kb < 1024; kb += 64) {
        bf16x8 k0 = *(const bf16x8*)(kp + (size_t)(kb + srow) * 64 + sc0);
        bf16x8 k1 = *(const bf16x8*)(kp + (size_t)(kb + srow) * 64 + sc0 + 8);
        bf16x8 v0 = *(const bf16x8*)(vp + (size_t)srow * 1024 + kb + sc0);
        bf16x8 v1 = *(const bf16x8*)(vp + (size_t)srow * 1024 + kb + sc0 + 8);
        __syncthreads();
        *(bf16x8*)&Ksm[srow * 72 + sc0] = k0;
        *(bf16x8*)&Ksm[srow * 72 + sc0 + 8] = k1;
        *(bf16x8*)&Vsm[srow * 72 + sc0] = v0;
        *(bf16x8*)&Vsm[srow * 72 + sc0 + 8] = v1;
        if (tid < 64) sksm[tid] = ksp[kb + tid];
        __syncthreads();

        // S = Q K^T for this 16q x 64k stripe
        f32x4 sacc[4] = {};
#pragma unroll
        for (int nt = 0; nt < 4; nt++) {
            bf16x8 kf0 = *(const bf16x8*)&Ksm[(nt * 16 + l16) * 72 + quad * 8];
            bf16x8 kf1 = *(const bf16x8*)&Ksm[(nt * 16 + l16) * 72 + 32 + quad * 8];
            sacc[nt] = __builtin_amdgcn_mfma_f32_16x16x32_bf16(qf[0], kf0, sacc[nt], 0, 0, 0);
            sacc[nt] = __builtin_amdgcn_mfma_f32_16x16x32_bf16(qf[1], kf1, sacc[nt], 0, 0, 0);
        }

        // bias + scale + mask
        float sv[4][4];
#pragma unroll
        for (int nt = 0; nt < 4; nt++) {
            int kcol = kb + nt * 16 + l16;
            float ksv = sksm[nt * 16 + l16];
#pragma unroll
            for (int r = 0; r < 4; r++) {
                int q = q0 + quad * 4 + r;
                float bsv = bsp[(size_t)q * 1024 + kcol];
                float mraw = mp[(size_t)q * 1024 + kcol];
                float val = (sacc[nt][r] + bsv * ksv) * 0.125f;
                sv[nt][r] = (mraw != 0.f) ? -3.0e38f : val;
            }
        }

        // online softmax update
        float mnew[4];
#pragma unroll
        for (int r = 0; r < 4; r++) {
            float mx = fmaxf(fmaxf(sv[0][r], sv[1][r]), fmaxf(sv[2][r], sv[3][r]));
#pragma unroll
            for (int d = 1; d < 16; d <<= 1) mx = fmaxf(mx, __shfl_xor(mx, d));
            mnew[r] = fmaxf(m_i[r], mx);
        }
#pragma unroll
        for (int nt = 0; nt < 4; nt++)
#pragma unroll
            for (int r = 0; r < 4; r++) sv[nt][r] = __expf(sv[nt][r] - mnew[r]);
#pragma unroll
        for (int r = 0; r < 4; r++) {
            float s = sv[0][r] + sv[1][r] + sv[2][r] + sv[3][r];
#pragma unroll
            for (int d = 1; d < 16; d <<= 1) s += __shfl_xor(s, d);
            float alpha = __expf(m_i[r] - mnew[r]);
            l_i[r] = l_i[r] * alpha + s;
            m_i[r] = mnew[r];
#pragma unroll
            for (int at = 0; at < 4; at++) oacc[at][r] *= alpha;
        }

        // P (C-layout) -> LDS -> A-layout fragments
#pragma unroll
        for (int nt = 0; nt < 4; nt++)
#pragma unroll
            for (int r = 0; r < 4; r++)
                pw[(quad * 4 + r) * 72 + nt * 16 + l16] = f2bf(sv[nt][r]);
        __syncthreads();  // P writes visible before A-layout reads
#pragma unroll
        for (int s = 0; s < 2; s++) {
            bf16x8 pf = *(const bf16x8*)&pw[l16 * 72 + s * 32 + quad * 8];
#pragma unroll
            for (int at = 0; at < 4; at++) {
                bf16x8 vf = *(const bf16x8*)&Vsm[(at * 16 + l16) * 72 + s * 32 + quad * 8];
                oacc[at] = __builtin_amdgcn_mfma_f32_16x16x32_bf16(pf, vf, oacc[at], 0, 0, 0);
            }
        }
    }

    // epilogue: ctx[b, q, h, a]
#pragma unroll
    for (int at = 0; at < 4; at++)
#pragma unroll
        for (int r = 0; r < 4; r++) {
            int q = q0 + quad * 4 + r;
            int a = at * 16 + l16;
            float val = oacc[at][r] / l_i[r];
            ctx[(((size_t)b * 1024 + q) * 16 + h) * 64 + a] = f2bf(val);
        }
}

// ---------------------------------------------------------------------------
extern "C" void kernel_launch(void* const* d_in, const int* in_sizes, int n_in,
                              void* d_out, int out_size, void* d_ws, size_t ws_size,
                              hipStream_t stream) {
    const float* states = (const float*)d_in[0];
    const float* key_states = (const float*)d_in[1];
    const float* masks = (const float*)d_in[2];
    const int* abias = (const int*)d_in[3];
    const float* Wq = (const float*)d_in[4];
    const float* Wk = (const float*)d_in[5];
    const float* Wv = (const float*)d_in[6];
    const float* Wout = (const float*)d_in[7];
    const float* be = (const float*)d_in[8];
    const float* bsc = (const float*)d_in[9];

    char* ws = (char*)d_ws;
    size_t off = 0;
    auto alloc = [&](size_t n) { void* p = ws + off; off += (n + 255) & ~(size_t)255; return p; };
    u16* wT = (u16*)alloc(4ull * 1024 * 1024 * 2);          // transposed weights bf16 (8 MB)
    u16* sbf = (u16*)alloc((size_t)BB * TT * DD * 2);       // states bf16 (16 MB)
    u16* kbf = (u16*)alloc((size_t)BB * TT * DD * 2);       // key_states bf16 (16 MB)
    u16* qb_ = (u16*)alloc((size_t)BB * HH * TT * AA * 2);  // q [B,H,T,A] (16 MB)
    u16* kb_ = (u16*)alloc((size_t)BB * HH * TT * AA * 2);  // k [B,H,T,A] (16 MB)
    u16* vb_ = (u16*)alloc((size_t)BB * HH * TT * AA * 2);  // v [B,H,T,A] (16 MB)
    u16* vT_ = (u16*)alloc((size_t)BB * HH * AA * TT * 2);  // vT [B,H,A,T] (16 MB)
    float* ks_ = (float*)alloc((size_t)BB * HH * TT * 4);   // ksum (0.5 MB)
    float* bs_ = (float*)alloc((size_t)BB * TT * TT * 4);   // bias scatter f32 (32 MB)

    u16* wqT = wT;
    u16* wkT = wT + 1048576;
    u16* wvT = wT + 2097152;
    u16* woT = wT + 3145728;
    // aliases: idx buffer (32 MB) over qb_+kb_ (dead until projections);
    //          ctx reuses vb_ (dead after tr_v)
    int* idx_ = (int*)qb_;
    u16* ctx_ = vb_;

    // 1) init scatter-idx (-1) and bias buffer (0)
    hipMemsetAsync(idx_, 0xFF, (size_t)BB * TT * TT * 4, stream);
    hipMemsetAsync(bs_, 0, (size_t)BB * TT * TT * 4, stream);
    // 2) deterministic scatter: last edge index wins (numpy semantics)
    scat_max<<<dim3(EE / 256), 256, 0, stream>>>(abias, idx_);
    scat_res<<<dim3(EE / 256), 256, 0, stream>>>(abias, idx_, be, bsc, bs_);
    // 3) weights f32 -> bf16 transposed
    tr_w<<<dim3(16, 16, 4), 256, 0, stream>>>(Wq, Wk, Wv, Wout, wT);
    // 4) activations f32 -> bf16
    cvt<<<dim3(4096), 256, 0, stream>>>(states, sbf);
    cvt<<<dim3(4096), 256, 0, stream>>>(key_states, kbf);
    // 5) projections (overwrite idx_ region — scatter complete)
    gemm128<<<dim3(8, 64), 256, 0, stream>>>(sbf, wqT, qb_, 1);
    gemm128<<<dim3(8, 64), 256, 0, stream>>>(kbf, wkT, kb_, 1);
    gemm128<<<dim3(8, 64), 256, 0, stream>>>(kbf, wvT, vb_, 1);
    // 6) v transpose
    tr_v<<<dim3(16, 128), 256, 0, stream>>>(vb_, vT_);
    // 7) ksum
    ksumk<<<dim3(512), 256, 0, stream>>>(kb_, ks_);
    // 8) attention (ctx_ = vb_, dead after tr_v)
    attn<<<dim3(16, 16, 8), 256, 0, stream>>>(qb_, kb_, vT_, ks_, bs_, masks, ctx_);
    // 9) output projection -> d_out (f32)
    gemm128<<<dim3(8, 64), 256, 0, stream>>>(ctx_, woT, d_out, 0);
}